// Round 5
// baseline (74.931 us; speedup 1.0000x reference)
//
#include <hip/hip_runtime.h>

#define IMG_H 512
#define IMG_W 512
#define NB    8
#define TILE  32
#define LROWS 34            // owner rows 0..31 + 2 halo rows below
#define LCOLS 36            // owner col j -> lds col j+2 (halo +-2)
#define NBLK  (NB * (IMG_H / TILE) * (IMG_W / TILE))   // 2048
#define N_MEAN 16777216.0   // B * 8 dirs * H * W
#define LOG2E 1.44269504f
#define LN2   0.69314718f

__device__ __forceinline__ float frcp(float x){ return __builtin_amdgcn_rcpf(x); }
__device__ __forceinline__ float fexp2(float x){ return __builtin_amdgcn_exp2f(x); }
__device__ __forceinline__ float flog2(float x){ return __builtin_amdgcn_logf(x); }

// Per-pixel pack {s, mw, e', nw}:
//   s  = sigmoid(c_map)
//   mw = (t ? -0.6 : -1.4) * log(sel+1e-4), sel = t ? s : 1-s   (eq-pair num, K=1 weight)
//   e' = (t ? -1 : +1) * exp(-s);  e' == 0  => OOB sentinel
//   nw = (t ? -0.07 : -0.28) * log(sel+1e-4)                    (nbr num, -0.35*k folded)
__global__ __launch_bounds__(256) void scloss_main(
    const float* __restrict__ cmap, const int* __restrict__ tgt,
    float* __restrict__ partials, unsigned* __restrict__ counter,
    float* __restrict__ out)
{
    __shared__ float4 pack[LROWS * LCOLS];
    __shared__ float  wsum[4];
    __shared__ int    lastBlock;

    const int tilesPerRow = IMG_W / TILE;                 // 16
    const int tilesPerImg = (IMG_H / TILE) * tilesPerRow; // 256
    int blk = blockIdx.x;
    int b   = blk / tilesPerImg;
    int ti  = blk % tilesPerImg;
    int tr  = (ti / tilesPerRow) * TILE;
    int tc  = (ti % tilesPerRow) * TILE;

    const float* cimg = cmap + (size_t)b * (IMG_H * IMG_W);
    const int*   timg = tgt  + (size_t)b * (IMG_H * IMG_W);

    // Stage rows tr..tr+33, cols tc-2..tc+33.
    for (int idx = threadIdx.x; idx < LROWS * LCOLS; idx += 256) {
        int lr = idx / LCOLS, lc = idx - lr * LCOLS;
        int gr = tr + lr, gc = tc + lc - 2;
        float4 v = make_float4(0.0f, 0.0f, 0.0f, 0.0f);
        if (gr < IMG_H && (unsigned)gc < (unsigned)IMG_W) {
            float x = cimg[gr * IMG_W + gc];
            bool  t = timg[gr * IMG_W + gc] != 0;
            float s   = frcp(1.0f + fexp2(x * -LOG2E));
            float sel = t ? s : (1.0f - s);
            float L   = LN2 * flog2(sel + 1e-4f);
            float e   = fexp2(s * -LOG2E);
            v = make_float4(s,
                            (t ? -0.6f : -1.4f) * L,
                            t ? -e : e,
                            (t ? -0.07f : -0.28f) * L);
        }
        pack[idx] = v;
    }
    __syncthreads();

    int j  = threadIdx.x & 31;
    int i0 = threadIdx.x >> 5;      // 0..7 -> owner rows 4*i0..4*i0+3
    float acc = 0.0f;

// One edge, named-scalar outputs only (compile-time offsets -> pure registers).
#define EDGE(VBX, Dd, Nn, WSK, MK) do {                                   \
        float4 vb  = (VBX);                                               \
        bool  tb   = vb.z < 0.0f;                                         \
        bool  qpos = (ta == tb);           /* both targets equal */       \
        bool  qnz  = vb.z != 0.0f;         /* neighbor in bounds */       \
        float ppp  = __builtin_fmaf(sa, vb.x, 1e-4f);                     \
        float ompp = __builtin_fmaf(-sa, vb.x, 1.0001f);                  \
        float argc = (qpos && ta) ? ppp : ompp;                           \
        float lg   = flog2(argc);                                         \
        float E    = fexp2(__builtin_fmaf(ppp, -LOG2E, 1e-4f * LOG2E));   \
        float een  = ta ? vb.z : epa;      /* e' of the t=0 endpoint */   \
        float ee   = qpos ? E : een;                                      \
        Dd         = __builtin_fmaf(-LN2, lg, ee);                        \
        float nm   = qpos ? __builtin_fmaf(WSK, vb.y, MK) : (nwa + vb.w); \
        Nn         = qnz ? nm : 0.0f;                                     \
    } while (0)

// 4 divisions with one reciprocal.
#define COMBINE do {                                                      \
        float d01 = D0 * D1, d23 = D2 * D3;                               \
        float R   = frcp(d01 * d23);                                      \
        float n01 = __builtin_fmaf(N1, D0, N0 * D1);                      \
        float n23 = __builtin_fmaf(N3, D2, N2 * D3);                      \
        acc = __builtin_fmaf(__builtin_fmaf(n23, d01, n01 * d23), R, acc);\
    } while (0)

// One pixel: 8 edges.  S1X/S2X = the (row+1) / (row+2) packs, register-reused
// where they are the thread's own pixels.
#define PIXEL(VA, S1X, S2X, base) do {                                    \
        float4 va_ = (VA);                                                \
        bool  ta  = va_.z < 0.0f;                                         \
        float sa  = va_.x, nwa = va_.w, epa = va_.z;                      \
        float mwa = va_.y, hmw = 0.5f * va_.y;                            \
        float D0, D1, D2, D3, N0, N1, N2, N3;                             \
        EDGE(base[1],           D0, N0, 1.0f, mwa);   /* E  K1 */         \
        EDGE(base[LCOLS + 1],   D1, N1, 1.0f, mwa);   /* SE K1 */         \
        EDGE(S1X,               D2, N2, 1.0f, mwa);   /* S  K1 */         \
        EDGE(base[LCOLS - 1],   D3, N3, 1.0f, mwa);   /* SW K1 */         \
        COMBINE;                                                          \
        EDGE(base[2],           D0, N0, 0.5f, hmw);   /* E  K2 */         \
        EDGE(base[2*LCOLS + 2], D1, N1, 0.5f, hmw);   /* SE K2 */         \
        EDGE(S2X,               D2, N2, 0.5f, hmw);   /* S  K2 */         \
        EDGE(base[2*LCOLS - 2], D3, N3, 0.5f, hmw);   /* SW K2 */         \
        COMBINE;                                                          \
    } while (0)

    {
        const float4* b0 = &pack[(i0 * 4) * LCOLS + (j + 2)];
        const float4* b1 = b0 + LCOLS;
        const float4* b2 = b1 + LCOLS;
        const float4* b3 = b2 + LCOLS;
        float4 va0 = b0[0], va1 = b1[0], va2 = b2[0], va3 = b3[0];
        PIXEL(va0, va1, va2,            b0);
        PIXEL(va1, va2, va3,            b1);
        PIXEL(va2, va3, b2[2 * LCOLS],  b2);
        PIXEL(va3, b3[LCOLS], b3[2 * LCOLS], b3);
    }
#undef PIXEL
#undef COMBINE
#undef EDGE

    // Block reduction: wave64 shuffle then cross-wave via LDS.
    #pragma unroll
    for (int o = 32; o > 0; o >>= 1) acc += __shfl_down(acc, o, 64);
    int lane = threadIdx.x & 63, wid = threadIdx.x >> 6;
    if (lane == 0) wsum[wid] = acc;
    __syncthreads();   // also: all threads done reading `pack`

    if (threadIdx.x == 0) {
        float bs = wsum[0] + wsum[1] + wsum[2] + wsum[3];
        __hip_atomic_store(&partials[blockIdx.x], bs,
                           __ATOMIC_RELEASE, __HIP_MEMORY_SCOPE_AGENT);
        unsigned old = __hip_atomic_fetch_add(counter, 1u,
                           __ATOMIC_ACQ_REL, __HIP_MEMORY_SCOPE_AGENT);
        lastBlock = (old == (unsigned)(NBLK - 1));
    }
    __syncthreads();

    if (lastBlock) {   // uniform across the block
        double a = 0.0;
        for (int idx = threadIdx.x; idx < NBLK; idx += 256)
            a += (double)__hip_atomic_load(&partials[idx],
                             __ATOMIC_RELAXED, __HIP_MEMORY_SCOPE_AGENT);
        double* sd = (double*)pack;    // reuse LDS (safe: past the sync)
        sd[threadIdx.x] = a;
        __syncthreads();
        for (int s2 = 128; s2 > 0; s2 >>= 1) {
            if (threadIdx.x < s2) sd[threadIdx.x] += sd[threadIdx.x + s2];
            __syncthreads();
        }
        if (threadIdx.x == 0) out[0] = (float)(sd[0] / N_MEAN);
    }
}

extern "C" void kernel_launch(void* const* d_in, const int* in_sizes, int n_in,
                              void* d_out, int out_size, void* d_ws, size_t ws_size,
                              hipStream_t stream) {
    const float* cmap = (const float*)d_in[0];
    const int*   tgt  = (const int*)d_in[1];
    float*    out      = (float*)d_out;
    float*    partials = (float*)d_ws;
    unsigned* counter  = (unsigned*)((char*)d_ws + NBLK * sizeof(float));

    hipMemsetAsync(counter, 0, sizeof(unsigned), stream);
    scloss_main<<<NBLK, 256, 0, stream>>>(cmap, tgt, partials, counter, out);
}

// Round 6
// 24.482 us; speedup vs baseline: 3.0607x; 3.0607x over previous
//
#include <hip/hip_runtime.h>

#define IMG_H 512
#define IMG_W 512
#define NB    8
#define TILE  32
#define LROWS 34            // owner rows 0..31 + 2 halo rows below
#define LCOLS 36            // owner col j -> lds col j+2 (halo +-2)
#define NBLK  (NB * (IMG_H / TILE) * (IMG_W / TILE))   // 2048
#define N_MEAN 16777216.0   // B * 8 dirs * H * W
#define LOG2E 1.44269504f
#define LN2   0.69314718f

__device__ __forceinline__ float frcp(float x){ return __builtin_amdgcn_rcpf(x); }
__device__ __forceinline__ float fexp2(float x){ return __builtin_amdgcn_exp2f(x); }
__device__ __forceinline__ float flog2(float x){ return __builtin_amdgcn_logf(x); }

// Per-pixel pack {s, mw, e', nw}:
//   s  = sigmoid(c_map)
//   mw = (t ? -0.6 : -1.4) * log(sel+1e-4), sel = t ? s : 1-s   (eq-pair num, K=1 weight)
//   e' = (t ? -1 : +1) * exp(-s);  e' == 0  => OOB sentinel
//   nw = (t ? -0.07 : -0.28) * log(sel+1e-4)                    (nbr num, -0.35*k folded)
__global__ __launch_bounds__(256) void scloss_main(
    const float* __restrict__ cmap, const int* __restrict__ tgt,
    float* __restrict__ partials)
{
    __shared__ float4 pack[LROWS * LCOLS];

    const int tilesPerRow = IMG_W / TILE;                 // 16
    const int tilesPerImg = (IMG_H / TILE) * tilesPerRow; // 256
    int blk = blockIdx.x;
    int b   = blk / tilesPerImg;
    int ti  = blk % tilesPerImg;
    int tr  = (ti / tilesPerRow) * TILE;
    int tc  = (ti % tilesPerRow) * TILE;

    const float* cimg = cmap + (size_t)b * (IMG_H * IMG_W);
    const int*   timg = tgt  + (size_t)b * (IMG_H * IMG_W);

    // Stage rows tr..tr+33, cols tc-2..tc+33.
    for (int idx = threadIdx.x; idx < LROWS * LCOLS; idx += 256) {
        int lr = idx / LCOLS, lc = idx - lr * LCOLS;
        int gr = tr + lr, gc = tc + lc - 2;
        float4 v = make_float4(0.0f, 0.0f, 0.0f, 0.0f);
        if (gr < IMG_H && (unsigned)gc < (unsigned)IMG_W) {
            float x = cimg[gr * IMG_W + gc];
            bool  t = timg[gr * IMG_W + gc] != 0;
            float s   = frcp(1.0f + fexp2(x * -LOG2E));
            float sel = t ? s : (1.0f - s);
            float L   = LN2 * flog2(sel + 1e-4f);
            float e   = fexp2(s * -LOG2E);
            v = make_float4(s,
                            (t ? -0.6f : -1.4f) * L,
                            t ? -e : e,
                            (t ? -0.07f : -0.28f) * L);
        }
        pack[idx] = v;
    }
    __syncthreads();

    int j  = threadIdx.x & 31;
    int i0 = threadIdx.x >> 5;      // 0..7 -> owner rows 4*i0..4*i0+3
    float acc = 0.0f;

// One edge, named-scalar outputs only (compile-time offsets -> pure registers).
#define EDGE(VBX, Dd, Nn, WSK, MK) do {                                   \
        float4 vb  = (VBX);                                               \
        bool  tb   = vb.z < 0.0f;                                         \
        bool  qpos = (ta == tb);           /* both targets equal */       \
        bool  qnz  = vb.z != 0.0f;         /* neighbor in bounds */       \
        float ppp  = __builtin_fmaf(sa, vb.x, 1e-4f);                     \
        float ompp = __builtin_fmaf(-sa, vb.x, 1.0001f);                  \
        float argc = (qpos && ta) ? ppp : ompp;                           \
        float lg   = flog2(argc);                                         \
        float E    = fexp2(__builtin_fmaf(ppp, -LOG2E, 1e-4f * LOG2E));   \
        float een  = ta ? vb.z : epa;      /* e' of the t=0 endpoint */   \
        float ee   = qpos ? E : een;                                      \
        Dd         = __builtin_fmaf(-LN2, lg, ee);                        \
        float nm   = qpos ? __builtin_fmaf(WSK, vb.y, MK) : (nwa + vb.w); \
        Nn         = qnz ? nm : 0.0f;                                     \
    } while (0)

// 4 divisions with one reciprocal.
#define COMBINE do {                                                      \
        float d01 = D0 * D1, d23 = D2 * D3;                               \
        float R   = frcp(d01 * d23);                                      \
        float n01 = __builtin_fmaf(N1, D0, N0 * D1);                      \
        float n23 = __builtin_fmaf(N3, D2, N2 * D3);                      \
        acc = __builtin_fmaf(__builtin_fmaf(n23, d01, n01 * d23), R, acc);\
    } while (0)

// One pixel: 8 edges.  S1X/S2X = the (row+1)/(row+2) packs, register-reused
// where they are the thread's own pixels.
#define PIXEL(VA, S1X, S2X, base) do {                                    \
        float4 va_ = (VA);                                                \
        bool  ta  = va_.z < 0.0f;                                         \
        float sa  = va_.x, nwa = va_.w, epa = va_.z;                      \
        float mwa = va_.y, hmw = 0.5f * va_.y;                            \
        float D0, D1, D2, D3, N0, N1, N2, N3;                             \
        EDGE(base[1],           D0, N0, 1.0f, mwa);   /* E  K1 */         \
        EDGE(base[LCOLS + 1],   D1, N1, 1.0f, mwa);   /* SE K1 */         \
        EDGE(S1X,               D2, N2, 1.0f, mwa);   /* S  K1 */         \
        EDGE(base[LCOLS - 1],   D3, N3, 1.0f, mwa);   /* SW K1 */         \
        COMBINE;                                                          \
        EDGE(base[2],           D0, N0, 0.5f, hmw);   /* E  K2 */         \
        EDGE(base[2*LCOLS + 2], D1, N1, 0.5f, hmw);   /* SE K2 */         \
        EDGE(S2X,               D2, N2, 0.5f, hmw);   /* S  K2 */         \
        EDGE(base[2*LCOLS - 2], D3, N3, 0.5f, hmw);   /* SW K2 */         \
        COMBINE;                                                          \
    } while (0)

    {
        const float4* b0 = &pack[(i0 * 4) * LCOLS + (j + 2)];
        const float4* b1 = b0 + LCOLS;
        const float4* b2 = b1 + LCOLS;
        const float4* b3 = b2 + LCOLS;
        float4 va0 = b0[0], va1 = b1[0], va2 = b2[0], va3 = b3[0];
        PIXEL(va0, va1, va2,            b0);
        PIXEL(va1, va2, va3,            b1);
        PIXEL(va2, va3, b2[2 * LCOLS],  b2);
        PIXEL(va3, b3[LCOLS], b3[2 * LCOLS], b3);
    }
#undef PIXEL
#undef COMBINE
#undef EDGE

    // Block reduction: wave64 shuffle then cross-wave via LDS.
    #pragma unroll
    for (int o = 32; o > 0; o >>= 1) acc += __shfl_down(acc, o, 64);
    __shared__ float wsum[4];
    int lane = threadIdx.x & 63, wid = threadIdx.x >> 6;
    if (lane == 0) wsum[wid] = acc;
    __syncthreads();
    if (threadIdx.x == 0)
        partials[blockIdx.x] = wsum[0] + wsum[1] + wsum[2] + wsum[3];
}

__global__ __launch_bounds__(256) void scloss_final(
    const float* __restrict__ partials, int n, float* __restrict__ out)
{
    double a = 0.0;
    for (int i = threadIdx.x; i < n; i += 256) a += (double)partials[i];
    __shared__ double sd[256];
    sd[threadIdx.x] = a;
    __syncthreads();
    for (int s = 128; s > 0; s >>= 1) {
        if (threadIdx.x < s) sd[threadIdx.x] += sd[threadIdx.x + s];
        __syncthreads();
    }
    if (threadIdx.x == 0) out[0] = (float)(sd[0] / N_MEAN);
}

extern "C" void kernel_launch(void* const* d_in, const int* in_sizes, int n_in,
                              void* d_out, int out_size, void* d_ws, size_t ws_size,
                              hipStream_t stream) {
    const float* cmap = (const float*)d_in[0];
    const int*   tgt  = (const int*)d_in[1];
    float* out      = (float*)d_out;
    float* partials = (float*)d_ws;

    scloss_main<<<NBLK, 256, 0, stream>>>(cmap, tgt, partials);
    scloss_final<<<1, 256, 0, stream>>>(partials, NBLK, out);
}